// Round 1
// baseline (3975.148 us; speedup 1.0000x reference)
//
#include <hip/hip_runtime.h>

#define HID 128
#define EMB 64
#define NPB 32
#define NG  8192
#define NCLS 16

// ---------------- degree / dinv ----------------
__global__ void k_deg(const int* __restrict__ dst, int E, int* __restrict__ deg) {
    int i = blockIdx.x * 256 + threadIdx.x;
    if (i < E) atomicAdd(&deg[dst[i]], 1);
}

__global__ void k_dinv(const int* __restrict__ deg, float* __restrict__ dinv, int N) {
    int i = blockIdx.x * 256 + threadIdx.x;
    if (i < N) dinv[i] = rsqrtf((float)(deg[i] + 1));  // +1 self-loop; always >= 1
}

// ---------------- layer-1 matmul fused with embedding gather ----------------
// out[n][j] = sum_k embed[ids[n]][k] * W1[k][j]
__global__ void k_mm1(const int* __restrict__ ids, const float* __restrict__ embed,
                      const float* __restrict__ W1, float* __restrict__ out, int N) {
    __shared__ float Ws[EMB * HID];   // 32 KB
    __shared__ float row[EMB];
    int tid = threadIdx.x;
    for (int t = tid; t < EMB * HID; t += 128) Ws[t] = W1[t];
    int base = blockIdx.x * NPB;
    for (int n = base; n < base + NPB; ++n) {
        if (n >= N) break;
        __syncthreads();                       // Ws ready / prev iter done
        if (tid < EMB) row[tid] = embed[ids[n] * EMB + tid];
        __syncthreads();
        float acc = 0.f;
#pragma unroll
        for (int k = 0; k < EMB; ++k) acc = fmaf(row[k], Ws[k * HID + tid], acc);
        out[n * HID + tid] = acc;
    }
}

// ---------------- layer-2 matmul: [N x 128] @ [128 x 128] ----------------
__global__ void k_mm2(const float* __restrict__ in, const float* __restrict__ W,
                      float* __restrict__ out, int N) {
    __shared__ float Ws[64 * HID];     // one K-half, 32 KB
    __shared__ float rows[NPB * 64];   // K-half of each node row, 8 KB
    int tid = threadIdx.x;
    int base = blockIdx.x * NPB;
    float acc[NPB];
#pragma unroll
    for (int n = 0; n < NPB; ++n) acc[n] = 0.f;
    for (int kh = 0; kh < 2; ++kh) {
        __syncthreads();
        for (int t = tid; t < 64 * HID; t += 128) Ws[t] = W[kh * 64 * HID + t];
        for (int t = tid; t < NPB * 64; t += 128) {
            int n = t >> 6, k = t & 63;
            int node = base + n; if (node >= N) node = N - 1;
            rows[t] = in[node * HID + kh * 64 + k];
        }
        __syncthreads();
        for (int k = 0; k < 64; ++k) {
            float w = Ws[k * HID + tid];
#pragma unroll
            for (int n = 0; n < NPB; ++n) acc[n] = fmaf(rows[n * 64 + k], w, acc[n]);
        }
    }
#pragma unroll
    for (int n = 0; n < NPB; ++n) {
        int node = base + n;
        if (node < N) out[node * HID + tid] = acc[n];
    }
}

// ---------------- edge propagate: agg[dst] += h[src] * dinv[src]*dinv[dst] ----------------
__global__ void k_prop(const int* __restrict__ src, const int* __restrict__ dst,
                       const float* __restrict__ dinv, const float* __restrict__ h,
                       float* __restrict__ agg, int E) {
    int idx = blockIdx.x * 256 + threadIdx.x;   // E*32 threads, 4 floats each
    if (idx >= E * 32) return;
    int e = idx >> 5, q = idx & 31;
    int s = src[e], d = dst[e];
    float w = dinv[s] * dinv[d];
    const float4 v = *(const float4*)&h[s * HID + q * 4];
    float* p = &agg[d * HID + q * 4];
    atomicAdd(p + 0, v.x * w);
    atomicAdd(p + 1, v.y * w);
    atomicAdd(p + 2, v.z * w);
    atomicAdd(p + 3, v.w * w);
}

// ---------------- self-loop + bias + relu: acc = relu(acc + htrans*dinv^2 + b) ----------------
__global__ void k_finish(float* __restrict__ accbuf, const float* __restrict__ htrans,
                         const float* __restrict__ dinv, const float* __restrict__ bias, int N) {
    int idx = blockIdx.x * 256 + threadIdx.x;
    if (idx >= N * HID) return;
    int n = idx >> 7, j = idx & 127;
    float di = dinv[n];
    accbuf[idx] = fmaxf(accbuf[idx] + htrans[idx] * di * di + bias[j], 0.0f);
}

// ---------------- global mean pool (sum + counts via atomics) ----------------
__global__ void k_pool(const float* __restrict__ x, const int* __restrict__ batch,
                       float* __restrict__ pooled, float* __restrict__ counts, int N) {
    int idx = blockIdx.x * 256 + threadIdx.x;   // N*32 threads, 4 floats each
    if (idx >= N * 32) return;
    int n = idx >> 5, q = idx & 31;
    int g = batch[n];
    const float4 v = *(const float4*)&x[n * HID + q * 4];
    float* p = &pooled[g * HID + q * 4];
    atomicAdd(p + 0, v.x);
    atomicAdd(p + 1, v.y);
    atomicAdd(p + 2, v.z);
    atomicAdd(p + 3, v.w);
    if (q == 0) atomicAdd(&counts[g], 1.0f);
}

// ---------------- output head: out = (pooled/count) @ Wout + bout ----------------
__global__ void k_out(const float* __restrict__ pooled, const float* __restrict__ counts,
                      const float* __restrict__ Wout, const float* __restrict__ bout,
                      float* __restrict__ out) {
    int idx = blockIdx.x * 256 + threadIdx.x;   // NG*16
    if (idx >= NG * NCLS) return;
    int g = idx >> 4, c = idx & 15;
    float inv = 1.0f / fmaxf(counts[g], 1.0f);
    float acc = 0.f;
#pragma unroll
    for (int k = 0; k < HID; ++k) acc = fmaf(pooled[g * HID + k], Wout[k * NCLS + c], acc);
    out[idx] = acc * inv + bout[c];
}

extern "C" void kernel_launch(void* const* d_in, const int* in_sizes, int n_in,
                              void* d_out, int out_size, void* d_ws, size_t ws_size,
                              hipStream_t stream) {
    const int*   node_ids = (const int*)d_in[0];
    const int*   edge     = (const int*)d_in[1];
    const int*   batch    = (const int*)d_in[2];
    const float* embed    = (const float*)d_in[3];
    const float* W1       = (const float*)d_in[4];
    const float* b1       = (const float*)d_in[5];
    const float* W2       = (const float*)d_in[6];
    const float* b2       = (const float*)d_in[7];
    const float* Wout     = (const float*)d_in[8];
    const float* bout     = (const float*)d_in[9];
    float* out = (float*)d_out;

    const int N = in_sizes[0];
    const int E = in_sizes[1] / 2;

    // workspace layout (fp32): dinv[N] | deg[N] | A[N*128] | B[N*128] | pooled[NG*128] | counts[NG]
    char* ws = (char*)d_ws;
    float* dinv   = (float*)ws;  ws += (size_t)N * 4;
    int*   deg    = (int*)ws;    ws += (size_t)N * 4;
    float* A      = (float*)ws;  ws += (size_t)N * HID * 4;
    float* B      = (float*)ws;  ws += (size_t)N * HID * 4;
    float* pooled = (float*)ws;  ws += (size_t)NG * HID * 4;
    float* counts = (float*)ws;

    const int* src = edge;
    const int* dst = edge + E;

    // degrees + dinv
    hipMemsetAsync(deg, 0, (size_t)N * 4, stream);
    k_deg<<<(E + 255) / 256, 256, 0, stream>>>(dst, E, deg);
    k_dinv<<<(N + 255) / 256, 256, 0, stream>>>(deg, dinv, N);

    // layer 1
    k_mm1<<<(N + NPB - 1) / NPB, 128, 0, stream>>>(node_ids, embed, W1, A, N);
    hipMemsetAsync(B, 0, (size_t)N * HID * 4, stream);
    k_prop<<<(E * 32 + 255) / 256, 256, 0, stream>>>(src, dst, dinv, A, B, E);
    k_finish<<<(N * HID + 255) / 256, 256, 0, stream>>>(B, A, dinv, b1, N);  // relu1 -> B

    // layer 2
    k_mm2<<<(N + NPB - 1) / NPB, 128, 0, stream>>>(B, W2, A, N);             // h2 -> A
    hipMemsetAsync(B, 0, (size_t)N * HID * 4, stream);
    k_prop<<<(E * 32 + 255) / 256, 256, 0, stream>>>(src, dst, dinv, A, B, E);
    k_finish<<<(N * HID + 255) / 256, 256, 0, stream>>>(B, A, dinv, b2, N);  // relu2 -> B

    // pool + head
    hipMemsetAsync(pooled, 0, (size_t)(NG * HID + NG) * 4, stream);
    k_pool<<<(N * 32 + 255) / 256, 256, 0, stream>>>(B, batch, pooled, counts, N);
    k_out<<<(NG * NCLS + 255) / 256, 256, 0, stream>>>(pooled, counts, Wout, bout, out);
}

// Round 2
// 868.558 us; speedup vs baseline: 4.5767x; 4.5767x over previous
//
#include <hip/hip_runtime.h>

#define HID 128
#define EMB 64
#define NPB 32
#define NG  8192
#define NCLS 16
#define SCAN_T 4096   // threads in scan phase A/C

// ---------------- degree ----------------
__global__ void k_deg(const int* __restrict__ dst, int E, int* __restrict__ deg) {
    int i = blockIdx.x * 256 + threadIdx.x;
    if (i < E) atomicAdd(&deg[dst[i]], 1);
}

__global__ void k_dinv(const int* __restrict__ deg, float* __restrict__ dinv, int N) {
    int i = blockIdx.x * 256 + threadIdx.x;
    if (i < N) dinv[i] = rsqrtf((float)(deg[i] + 1));  // +1 self-loop
}

// ---------------- exclusive scan of deg -> rowptr (3 phases) ----------------
__global__ void k_scanA(const int* __restrict__ deg, int* __restrict__ tsum, int N, int seg) {
    int t = blockIdx.x * 256 + threadIdx.x;            // SCAN_T threads
    int beg = t * seg, end = min(beg + seg, N);
    int s = 0;
    for (int i = beg; i < end; ++i) s += deg[i];
    tsum[t] = s;
}

__global__ void k_scanB(int* __restrict__ tsum) {      // 1 block, 256 threads, SCAN_T entries
    __shared__ int sh[256];
    int tid = threadIdx.x;
    const int PER = SCAN_T / 256;                      // 16
    int vals[PER];
    int local = 0;
    int base = tid * PER;
#pragma unroll
    for (int i = 0; i < PER; ++i) { vals[i] = tsum[base + i]; local += vals[i]; }
    sh[tid] = local; __syncthreads();
    for (int d = 1; d < 256; d <<= 1) {
        int v = (tid >= d) ? sh[tid - d] : 0;
        __syncthreads();
        sh[tid] += v;
        __syncthreads();
    }
    int off = sh[tid] - local;                         // exclusive
#pragma unroll
    for (int i = 0; i < PER; ++i) { int v = vals[i]; tsum[base + i] = off; off += v; }
}

__global__ void k_scanC(const int* __restrict__ deg, const int* __restrict__ tsum,
                        int* __restrict__ rowptr, int N, int seg, int E) {
    int t = blockIdx.x * 256 + threadIdx.x;
    int beg = t * seg, end = min(beg + seg, N);
    int off = tsum[t];
    for (int i = beg; i < end; ++i) { rowptr[i] = off; off += deg[i]; }
    if (t == 0) rowptr[N] = E;
}

// ---------------- CSR fill (counting sort by dst) ----------------
__global__ void k_fill(const int* __restrict__ src, const int* __restrict__ dst,
                       const int* __restrict__ rowptr, int* __restrict__ cursor,
                       int* __restrict__ csr, int E) {
    int e = blockIdx.x * 256 + threadIdx.x;
    if (e < E) {
        int d = dst[e];
        int pos = atomicAdd(&cursor[d], 1);
        csr[rowptr[d] + pos] = src[e];
    }
}

// ---------------- layer-1 matmul fused with embedding gather ----------------
__global__ void k_mm1(const int* __restrict__ ids, const float* __restrict__ embed,
                      const float* __restrict__ W1, float* __restrict__ out, int N) {
    __shared__ float Ws[EMB * HID];   // 32 KB
    __shared__ float row[EMB];
    int tid = threadIdx.x;
    for (int t = tid; t < EMB * HID; t += 128) Ws[t] = W1[t];
    int base = blockIdx.x * NPB;
    for (int n = base; n < base + NPB; ++n) {
        if (n >= N) break;
        __syncthreads();
        if (tid < EMB) row[tid] = embed[ids[n] * EMB + tid];
        __syncthreads();
        float acc = 0.f;
#pragma unroll
        for (int k = 0; k < EMB; ++k) acc = fmaf(row[k], Ws[k * HID + tid], acc);
        out[n * HID + tid] = acc;
    }
}

// ---------------- layer-2 matmul: [N x 128] @ [128 x 128] ----------------
__global__ void k_mm2(const float* __restrict__ in, const float* __restrict__ W,
                      float* __restrict__ out, int N) {
    __shared__ float Ws[64 * HID];     // 32 KB
    __shared__ float rows[NPB * 64];   // 8 KB
    int tid = threadIdx.x;
    int base = blockIdx.x * NPB;
    float acc[NPB];
#pragma unroll
    for (int n = 0; n < NPB; ++n) acc[n] = 0.f;
    for (int kh = 0; kh < 2; ++kh) {
        __syncthreads();
        for (int t = tid; t < 64 * HID; t += 128) Ws[t] = W[kh * 64 * HID + t];
        for (int t = tid; t < NPB * 64; t += 128) {
            int n = t >> 6, k = t & 63;
            int node = base + n; if (node >= N) node = N - 1;
            rows[t] = in[node * HID + kh * 64 + k];
        }
        __syncthreads();
        for (int k = 0; k < 64; ++k) {
            float w = Ws[k * HID + tid];
#pragma unroll
            for (int n = 0; n < NPB; ++n) acc[n] = fmaf(rows[n * 64 + k], w, acc[n]);
        }
    }
#pragma unroll
    for (int n = 0; n < NPB; ++n) {
        int node = base + n;
        if (node < N) out[node * HID + tid] = acc[n];
    }
}

// ---------------- CSR gather propagate + self-loop + bias + relu ----------------
// out[d] = relu( sum_{s in N(d)} h[s]*dinv[s]*dinv[d] + h[d]*dinv[d]^2 + b )
__global__ void k_gather(const float* __restrict__ h, const int* __restrict__ csr,
                         const int* __restrict__ rowptr, const float* __restrict__ dinv,
                         const float* __restrict__ bias, float* __restrict__ out, int N) {
    int wid = (blockIdx.x * blockDim.x + threadIdx.x) >> 6;  // one wave per node
    if (wid >= N) return;
    int lane = threadIdx.x & 63;
    int d = wid;
    int beg = rowptr[d], end = rowptr[d + 1];
    float dd = dinv[d];
    const float2* hrow = (const float2*)h;
    float2 hv = hrow[(size_t)d * 64 + lane];
    float w0 = dd * dd;
    float ax = hv.x * w0, ay = hv.y * w0;
    for (int i = beg; i < end; ++i) {
        int s = csr[i];
        float w = dinv[s] * dd;
        float2 v = hrow[(size_t)s * 64 + lane];
        ax = fmaf(v.x, w, ax);
        ay = fmaf(v.y, w, ay);
    }
    float2 b = ((const float2*)bias)[lane];
    float2 r;
    r.x = fmaxf(ax + b.x, 0.f);
    r.y = fmaxf(ay + b.y, 0.f);
    ((float2*)out)[(size_t)d * 64 + lane] = r;
}

// ---------------- global mean pool (sum + counts via atomics) ----------------
__global__ void k_pool(const float* __restrict__ x, const int* __restrict__ batch,
                       float* __restrict__ pooled, float* __restrict__ counts, int N) {
    int idx = blockIdx.x * 256 + threadIdx.x;
    if (idx >= N * 32) return;
    int n = idx >> 5, q = idx & 31;
    int g = batch[n];
    const float4 v = *(const float4*)&x[n * HID + q * 4];
    float* p = &pooled[g * HID + q * 4];
    atomicAdd(p + 0, v.x);
    atomicAdd(p + 1, v.y);
    atomicAdd(p + 2, v.z);
    atomicAdd(p + 3, v.w);
    if (q == 0) atomicAdd(&counts[g], 1.0f);
}

// ---------------- output head ----------------
__global__ void k_out(const float* __restrict__ pooled, const float* __restrict__ counts,
                      const float* __restrict__ Wout, const float* __restrict__ bout,
                      float* __restrict__ out) {
    int idx = blockIdx.x * 256 + threadIdx.x;
    if (idx >= NG * NCLS) return;
    int g = idx >> 4, c = idx & 15;
    float inv = 1.0f / fmaxf(counts[g], 1.0f);
    float acc = 0.f;
#pragma unroll
    for (int k = 0; k < HID; ++k) acc = fmaf(pooled[g * HID + k], Wout[k * NCLS + c], acc);
    out[idx] = acc * inv + bout[c];
}

extern "C" void kernel_launch(void* const* d_in, const int* in_sizes, int n_in,
                              void* d_out, int out_size, void* d_ws, size_t ws_size,
                              hipStream_t stream) {
    const int*   node_ids = (const int*)d_in[0];
    const int*   edge     = (const int*)d_in[1];
    const int*   batch    = (const int*)d_in[2];
    const float* embed    = (const float*)d_in[3];
    const float* W1       = (const float*)d_in[4];
    const float* b1       = (const float*)d_in[5];
    const float* W2       = (const float*)d_in[6];
    const float* b2       = (const float*)d_in[7];
    const float* Wout     = (const float*)d_in[8];
    const float* bout     = (const float*)d_in[9];
    float* out = (float*)d_out;

    const int N = in_sizes[0];
    const int E = in_sizes[1] / 2;
    const int seg = (N + SCAN_T - 1) / SCAN_T;

    // workspace layout (fp32/int32):
    // dinv[N] | deg[N] (reused as cursor) | rowptr[N+1] | tsum[SCAN_T] | csr[E]
    // | A[N*128] | B[N*128] | pooled[NG*128] | counts[NG]
    char* ws = (char*)d_ws;
    float* dinv   = (float*)ws;  ws += (size_t)N * 4;
    int*   deg    = (int*)ws;    ws += (size_t)N * 4;
    int*   rowptr = (int*)ws;    ws += (size_t)(N + 1) * 4;
    int*   tsum   = (int*)ws;    ws += (size_t)SCAN_T * 4;
    int*   csr    = (int*)ws;    ws += (size_t)E * 4;
    float* A      = (float*)ws;  ws += (size_t)N * HID * 4;
    float* B      = (float*)ws;  ws += (size_t)N * HID * 4;
    float* pooled = (float*)ws;  ws += (size_t)NG * HID * 4;
    float* counts = (float*)ws;

    const int* src = edge;
    const int* dst = edge + E;

    // ---- CSR build ----
    hipMemsetAsync(deg, 0, (size_t)N * 4, stream);
    k_deg<<<(E + 255) / 256, 256, 0, stream>>>(dst, E, deg);
    k_dinv<<<(N + 255) / 256, 256, 0, stream>>>(deg, dinv, N);
    k_scanA<<<SCAN_T / 256, 256, 0, stream>>>(deg, tsum, N, seg);
    k_scanB<<<1, 256, 0, stream>>>(tsum);
    k_scanC<<<SCAN_T / 256, 256, 0, stream>>>(deg, tsum, rowptr, N, seg, E);
    hipMemsetAsync(deg, 0, (size_t)N * 4, stream);   // reuse as cursor
    k_fill<<<(E + 255) / 256, 256, 0, stream>>>(src, dst, rowptr, deg, csr, E);

    // ---- layer 1 ----
    k_mm1<<<(N + NPB - 1) / NPB, 128, 0, stream>>>(node_ids, embed, W1, A, N);
    k_gather<<<(N * 64 + 255) / 256, 256, 0, stream>>>(A, csr, rowptr, dinv, b1, B, N);

    // ---- layer 2 ----
    k_mm2<<<(N + NPB - 1) / NPB, 128, 0, stream>>>(B, W2, A, N);
    k_gather<<<(N * 64 + 255) / 256, 256, 0, stream>>>(A, csr, rowptr, dinv, b2, B, N);

    // ---- pool + head ----
    hipMemsetAsync(pooled, 0, (size_t)(NG * HID + NG) * 4, stream);
    k_pool<<<(N * 32 + 255) / 256, 256, 0, stream>>>(B, batch, pooled, counts, N);
    k_out<<<(NG * NCLS + 255) / 256, 256, 0, stream>>>(pooled, counts, Wout, bout, out);
}

// Round 3
// 454.790 us; speedup vs baseline: 8.7406x; 1.9098x over previous
//
#include <hip/hip_runtime.h>

#define HID 128
#define EMB 64
#define NG  8192
#define NCLS 16
#define SCAN_T 4096
#define MMB 64        // nodes per matmul block

// ---------------- degree ----------------
__global__ void k_deg(const int* __restrict__ dst, int E, int* __restrict__ deg) {
    int i = blockIdx.x * 256 + threadIdx.x;
    if (i < E) atomicAdd(&deg[dst[i]], 1);
}

__global__ void k_dinv(const int* __restrict__ deg, float* __restrict__ dinv, int N) {
    int i = blockIdx.x * 256 + threadIdx.x;
    if (i < N) dinv[i] = rsqrtf((float)(deg[i] + 1));  // +1 self-loop
}

// ---------------- exclusive scan of deg -> rowptr ----------------
__global__ void k_scanA(const int* __restrict__ deg, int* __restrict__ tsum, int N, int seg) {
    int t = blockIdx.x * 256 + threadIdx.x;
    int beg = t * seg, end = min(beg + seg, N);
    int s = 0;
    for (int i = beg; i < end; ++i) s += deg[i];
    tsum[t] = s;
}

__global__ void k_scanB(int* __restrict__ tsum) {
    __shared__ int sh[256];
    int tid = threadIdx.x;
    const int PER = SCAN_T / 256;
    int vals[PER];
    int local = 0;
    int base = tid * PER;
#pragma unroll
    for (int i = 0; i < PER; ++i) { vals[i] = tsum[base + i]; local += vals[i]; }
    sh[tid] = local; __syncthreads();
    for (int d = 1; d < 256; d <<= 1) {
        int v = (tid >= d) ? sh[tid - d] : 0;
        __syncthreads();
        sh[tid] += v;
        __syncthreads();
    }
    int off = sh[tid] - local;
#pragma unroll
    for (int i = 0; i < PER; ++i) { int v = vals[i]; tsum[base + i] = off; off += v; }
}

__global__ void k_scanC(const int* __restrict__ deg, const int* __restrict__ tsum,
                        int* __restrict__ rowptr, int N, int seg, int E) {
    int t = blockIdx.x * 256 + threadIdx.x;
    int beg = t * seg, end = min(beg + seg, N);
    int off = tsum[t];
    for (int i = beg; i < end; ++i) { rowptr[i] = off; off += deg[i]; }
    if (t == 0) rowptr[N] = E;
}

// ---------------- CSR fill ----------------
__global__ void k_fill(const int* __restrict__ src, const int* __restrict__ dst,
                       const int* __restrict__ rowptr, int* __restrict__ cursor,
                       int* __restrict__ csr, int E) {
    int e = blockIdx.x * 256 + threadIdx.x;
    if (e < E) {
        int d = dst[e];
        int pos = atomicAdd(&cursor[d], 1);
        csr[rowptr[d] + pos] = src[e];
    }
}

// ---------------- graph segment boundaries from sorted batch ----------------
__global__ void k_bounds(const int* __restrict__ batch, int* __restrict__ gstart, int N) {
    int n = blockIdx.x * 256 + threadIdx.x;
    if (n > N) return;
    int bc = (n < N) ? batch[n] : NG;
    int bp = (n > 0) ? batch[n - 1] : -1;
    for (int g = bp + 1; g <= bc; ++g) gstart[g] = n;
}

// ---------------- layer-1 matmul (embedding gather fused): [Nx64]@[64x128] ----------------
__global__ __launch_bounds__(256) void k_mm1(const int* __restrict__ ids,
                                             const float* __restrict__ embed,
                                             const float* __restrict__ W1,
                                             float* __restrict__ out, int N) {
    __shared__ float rows_t[EMB][68];    // transposed [k][n], 17 KB
    __shared__ float Ws[EMB * HID];      // full W1, 32 KB
    int tid = threadIdx.x;
    int base = blockIdx.x * MMB;
    // stage W1
    {
        const float4* wp = (const float4*)W1;
        float4* wsp = (float4*)Ws;
#pragma unroll
        for (int j = 0; j < 8; ++j) wsp[tid + 256 * j] = wp[tid + 256 * j];
    }
    // stage embedding rows transposed: thread -> node tid/4, k-range (tid&3)*16
    {
        int n = tid >> 2;
        int k0 = (tid & 3) * 16;
        int node = base + n; if (node >= N) node = N - 1;
        const float4* ep = (const float4*)&embed[(size_t)ids[node] * EMB + k0];
#pragma unroll
        for (int j = 0; j < 4; ++j) {
            float4 v = ep[j];
            int k = k0 + j * 4;
            rows_t[k + 0][n] = v.x; rows_t[k + 1][n] = v.y;
            rows_t[k + 2][n] = v.z; rows_t[k + 3][n] = v.w;
        }
    }
    __syncthreads();
    int n8 = (tid & 7) * 8;
    int c4 = (tid >> 3) * 4;
    float acc[8][4];
#pragma unroll
    for (int i = 0; i < 8; ++i)
#pragma unroll
        for (int j = 0; j < 4; ++j) acc[i][j] = 0.f;
    for (int k = 0; k < EMB; ++k) {
        float4 w = *(const float4*)&Ws[k * HID + c4];
        float4 r0 = *(const float4*)&rows_t[k][n8];
        float4 r1 = *(const float4*)&rows_t[k][n8 + 4];
        float rr[8] = {r0.x, r0.y, r0.z, r0.w, r1.x, r1.y, r1.z, r1.w};
#pragma unroll
        for (int i = 0; i < 8; ++i) {
            acc[i][0] = fmaf(rr[i], w.x, acc[i][0]);
            acc[i][1] = fmaf(rr[i], w.y, acc[i][1]);
            acc[i][2] = fmaf(rr[i], w.z, acc[i][2]);
            acc[i][3] = fmaf(rr[i], w.w, acc[i][3]);
        }
    }
#pragma unroll
    for (int i = 0; i < 8; ++i) {
        int node = base + n8 + i;
        if (node < N)
            *(float4*)&out[(size_t)node * HID + c4] =
                make_float4(acc[i][0], acc[i][1], acc[i][2], acc[i][3]);
    }
}

// ---------------- layer-2 matmul: [Nx128]@[128x128] ----------------
__global__ __launch_bounds__(256) void k_mm2(const float* __restrict__ in,
                                             const float* __restrict__ W,
                                             float* __restrict__ out, int N) {
    __shared__ float rows_t[HID][68];    // transposed [k][n], 34 KB
    __shared__ float Ws[32 * HID];       // quarter of W, 16 KB
    int tid = threadIdx.x;
    int base = blockIdx.x * MMB;
    // stage rows transposed: thread -> node tid/4, k-range (tid&3)*32
    {
        int n = tid >> 2;
        int k0 = (tid & 3) * 32;
        int node = base + n; if (node >= N) node = N - 1;
        const float4* ip = (const float4*)&in[(size_t)node * HID + k0];
#pragma unroll
        for (int j = 0; j < 8; ++j) {
            float4 v = ip[j];
            int k = k0 + j * 4;
            rows_t[k + 0][n] = v.x; rows_t[k + 1][n] = v.y;
            rows_t[k + 2][n] = v.z; rows_t[k + 3][n] = v.w;
        }
    }
    int n8 = (tid & 7) * 8;
    int c4 = (tid >> 3) * 4;
    float acc[8][4];
#pragma unroll
    for (int i = 0; i < 8; ++i)
#pragma unroll
        for (int j = 0; j < 4; ++j) acc[i][j] = 0.f;
    for (int q = 0; q < 4; ++q) {
        __syncthreads();
        {
            const float4* wp = (const float4*)&W[q * 32 * HID];
            float4* wsp = (float4*)Ws;
#pragma unroll
            for (int j = 0; j < 4; ++j) wsp[tid + 256 * j] = wp[tid + 256 * j];
        }
        __syncthreads();
        for (int k = 0; k < 32; ++k) {
            float4 w = *(const float4*)&Ws[k * HID + c4];
            float4 r0 = *(const float4*)&rows_t[q * 32 + k][n8];
            float4 r1 = *(const float4*)&rows_t[q * 32 + k][n8 + 4];
            float rr[8] = {r0.x, r0.y, r0.z, r0.w, r1.x, r1.y, r1.z, r1.w};
#pragma unroll
            for (int i = 0; i < 8; ++i) {
                acc[i][0] = fmaf(rr[i], w.x, acc[i][0]);
                acc[i][1] = fmaf(rr[i], w.y, acc[i][1]);
                acc[i][2] = fmaf(rr[i], w.z, acc[i][2]);
                acc[i][3] = fmaf(rr[i], w.w, acc[i][3]);
            }
        }
    }
#pragma unroll
    for (int i = 0; i < 8; ++i) {
        int node = base + n8 + i;
        if (node < N)
            *(float4*)&out[(size_t)node * HID + c4] =
                make_float4(acc[i][0], acc[i][1], acc[i][2], acc[i][3]);
    }
}

// ---------------- CSR gather propagate + self-loop + bias + relu ----------------
__global__ void k_gather(const float* __restrict__ h, const int* __restrict__ csr,
                         const int* __restrict__ rowptr, const float* __restrict__ dinv,
                         const float* __restrict__ bias, float* __restrict__ out, int N) {
    int wid = (blockIdx.x * blockDim.x + threadIdx.x) >> 6;
    if (wid >= N) return;
    int lane = threadIdx.x & 63;
    int d = wid;
    int beg = rowptr[d], end = rowptr[d + 1];
    float dd = dinv[d];
    const float2* hrow = (const float2*)h;
    float2 hv = hrow[(size_t)d * 64 + lane];
    float w0 = dd * dd;
    float ax = hv.x * w0, ay = hv.y * w0;
    for (int i = beg; i < end; ++i) {
        int s = csr[i];
        float w = dinv[s] * dd;
        float2 v = hrow[(size_t)s * 64 + lane];
        ax = fmaf(v.x, w, ax);
        ay = fmaf(v.y, w, ay);
    }
    float2 b = ((const float2*)bias)[lane];
    float2 r;
    r.x = fmaxf(ax + b.x, 0.f);
    r.y = fmaxf(ay + b.y, 0.f);
    ((float2*)out)[(size_t)d * 64 + lane] = r;
}

// ---------------- fused mean-pool + head: one wave per graph ----------------
__global__ void k_pool2(const float* __restrict__ x, const int* __restrict__ gstart,
                        const float* __restrict__ Wout, const float* __restrict__ bout,
                        float* __restrict__ out) {
    int wid = (blockIdx.x * blockDim.x + threadIdx.x) >> 6;  // graph id
    if (wid >= NG) return;
    int lane = threadIdx.x & 63;
    int beg = gstart[wid], end = gstart[wid + 1];
    const float2* rows = (const float2*)x;
    float sx = 0.f, sy = 0.f;
    for (int n = beg; n < end; ++n) {
        float2 v = rows[(size_t)n * 64 + lane];
        sx += v.x; sy += v.y;
    }
    float inv = (end > beg) ? 1.f / (float)(end - beg) : 1.f;
    sx *= inv; sy *= inv;
    // lane's two Wout rows: 2*lane and 2*lane+1
    float wo0[NCLS], wo1[NCLS];
    {
        const float4* p0 = (const float4*)&Wout[(size_t)(2 * lane) * NCLS];
        const float4* p1 = (const float4*)&Wout[(size_t)(2 * lane + 1) * NCLS];
#pragma unroll
        for (int j = 0; j < 4; ++j) {
            float4 a = p0[j]; wo0[4*j] = a.x; wo0[4*j+1] = a.y; wo0[4*j+2] = a.z; wo0[4*j+3] = a.w;
            float4 b = p1[j]; wo1[4*j] = b.x; wo1[4*j+1] = b.y; wo1[4*j+2] = b.z; wo1[4*j+3] = b.w;
        }
    }
#pragma unroll
    for (int c = 0; c < NCLS; ++c) {
        float p = fmaf(sx, wo0[c], sy * wo1[c]);
#pragma unroll
        for (int s = 1; s < 64; s <<= 1) p += __shfl_xor(p, s, 64);
        if (lane == c) out[(size_t)wid * NCLS + c] = p + bout[c];
    }
}

static inline size_t align_up(size_t v, size_t a) { return (v + a - 1) & ~(a - 1); }

extern "C" void kernel_launch(void* const* d_in, const int* in_sizes, int n_in,
                              void* d_out, int out_size, void* d_ws, size_t ws_size,
                              hipStream_t stream) {
    const int*   node_ids = (const int*)d_in[0];
    const int*   edge     = (const int*)d_in[1];
    const int*   batch    = (const int*)d_in[2];
    const float* embed    = (const float*)d_in[3];
    const float* W1       = (const float*)d_in[4];
    const float* b1       = (const float*)d_in[5];
    const float* W2       = (const float*)d_in[6];
    const float* b2       = (const float*)d_in[7];
    const float* Wout     = (const float*)d_in[8];
    const float* bout     = (const float*)d_in[9];
    float* out = (float*)d_out;

    const int N = in_sizes[0];
    const int E = in_sizes[1] / 2;
    const int seg = (N + SCAN_T - 1) / SCAN_T;

    // 256B-aligned workspace layout
    char* wsb = (char*)d_ws;
    size_t off = 0;
    float* dinv   = (float*)(wsb + off); off = align_up(off + (size_t)N * 4, 256);
    int*   deg    = (int*)(wsb + off);   off = align_up(off + (size_t)N * 4, 256);
    int*   rowptr = (int*)(wsb + off);   off = align_up(off + (size_t)(N + 1) * 4, 256);
    int*   tsum   = (int*)(wsb + off);   off = align_up(off + (size_t)SCAN_T * 4, 256);
    int*   gstart = (int*)(wsb + off);   off = align_up(off + (size_t)(NG + 1) * 4, 256);
    int*   csr    = (int*)(wsb + off);   off = align_up(off + (size_t)E * 4, 256);
    float* A      = (float*)(wsb + off); off = align_up(off + (size_t)N * HID * 4, 256);
    float* B      = (float*)(wsb + off); off = align_up(off + (size_t)N * HID * 4, 256);

    const int* src = edge;
    const int* dst = edge + E;

    // ---- CSR build + boundaries ----
    hipMemsetAsync(deg, 0, (size_t)N * 4, stream);
    k_deg<<<(E + 255) / 256, 256, 0, stream>>>(dst, E, deg);
    k_dinv<<<(N + 255) / 256, 256, 0, stream>>>(deg, dinv, N);
    k_scanA<<<SCAN_T / 256, 256, 0, stream>>>(deg, tsum, N, seg);
    k_scanB<<<1, 256, 0, stream>>>(tsum);
    k_scanC<<<SCAN_T / 256, 256, 0, stream>>>(deg, tsum, rowptr, N, seg, E);
    hipMemsetAsync(deg, 0, (size_t)N * 4, stream);   // reuse as cursor
    k_fill<<<(E + 255) / 256, 256, 0, stream>>>(src, dst, rowptr, deg, csr, E);
    k_bounds<<<(N + 1 + 255) / 256, 256, 0, stream>>>(batch, gstart, N);

    // ---- layer 1 ----
    k_mm1<<<(N + MMB - 1) / MMB, 256, 0, stream>>>(node_ids, embed, W1, A, N);
    k_gather<<<(N * 64 + 255) / 256, 256, 0, stream>>>(A, csr, rowptr, dinv, b1, B, N);

    // ---- layer 2 ----
    k_mm2<<<(N + MMB - 1) / MMB, 256, 0, stream>>>(B, W2, A, N);
    k_gather<<<(N * 64 + 255) / 256, 256, 0, stream>>>(A, csr, rowptr, dinv, b2, B, N);

    // ---- fused pool + head ----
    k_pool2<<<(NG * 64 + 255) / 256, 256, 0, stream>>>(B, gstart, Wout, bout, out);
}

// Round 4
// 425.895 us; speedup vs baseline: 9.3336x; 1.0678x over previous
//
#include <hip/hip_runtime.h>
#include <hip/hip_fp16.h>

#define HID 128
#define EMB 64
#define NG  8192
#define NCLS 16
#define SCAN_T 4096
#define MMB 64        // nodes per matmul block

// ---------------- degree ----------------
__global__ void k_deg(const int* __restrict__ dst, int E, int* __restrict__ deg) {
    int i = blockIdx.x * 256 + threadIdx.x;
    if (i < E) atomicAdd(&deg[dst[i]], 1);
}

__global__ void k_dinv(const int* __restrict__ deg, float* __restrict__ dinv, int N) {
    int i = blockIdx.x * 256 + threadIdx.x;
    if (i < N) dinv[i] = rsqrtf((float)(deg[i] + 1));  // +1 self-loop
}

// ---------------- exclusive scan of deg -> rowptr ----------------
__global__ void k_scanA(const int* __restrict__ deg, int* __restrict__ tsum, int N, int seg) {
    int t = blockIdx.x * 256 + threadIdx.x;
    int beg = t * seg, end = min(beg + seg, N);
    int s = 0;
    for (int i = beg; i < end; ++i) s += deg[i];
    tsum[t] = s;
}

__global__ void k_scanB(int* __restrict__ tsum) {
    __shared__ int sh[256];
    int tid = threadIdx.x;
    const int PER = SCAN_T / 256;
    int vals[PER];
    int local = 0;
    int base = tid * PER;
#pragma unroll
    for (int i = 0; i < PER; ++i) { vals[i] = tsum[base + i]; local += vals[i]; }
    sh[tid] = local; __syncthreads();
    for (int d = 1; d < 256; d <<= 1) {
        int v = (tid >= d) ? sh[tid - d] : 0;
        __syncthreads();
        sh[tid] += v;
        __syncthreads();
    }
    int off = sh[tid] - local;
#pragma unroll
    for (int i = 0; i < PER; ++i) { int v = vals[i]; tsum[base + i] = off; off += v; }
}

__global__ void k_scanC(const int* __restrict__ deg, const int* __restrict__ tsum,
                        int* __restrict__ rowptr, int N, int seg, int E) {
    int t = blockIdx.x * 256 + threadIdx.x;
    int beg = t * seg, end = min(beg + seg, N);
    int off = tsum[t];
    for (int i = beg; i < end; ++i) { rowptr[i] = off; off += deg[i]; }
    if (t == 0) rowptr[N] = E;
}

// ---------------- CSR fill ----------------
__global__ void k_fill(const int* __restrict__ src, const int* __restrict__ dst,
                       const int* __restrict__ rowptr, int* __restrict__ cursor,
                       int* __restrict__ csr, int E) {
    int e = blockIdx.x * 256 + threadIdx.x;
    if (e < E) {
        int d = dst[e];
        int pos = atomicAdd(&cursor[d], 1);
        csr[rowptr[d] + pos] = src[e];
    }
}

// ---------------- graph segment boundaries from sorted batch ----------------
__global__ void k_bounds(const int* __restrict__ batch, int* __restrict__ gstart, int N) {
    int n = blockIdx.x * 256 + threadIdx.x;
    if (n > N) return;
    int bc = (n < N) ? batch[n] : NG;
    int bp = (n > 0) ? batch[n - 1] : -1;
    for (int g = bp + 1; g <= bc; ++g) gstart[g] = n;
}

// ---------------- layer-1 propagate in 64-dim embed space (L2-resident table) ----
// agg0[d] = sum_{s in N(d)} embed[ids[s]]*dinv[s]*dinv[d] + embed[ids[d]]*dinv[d]^2
__global__ void k_gather64(const int* __restrict__ ids, const float* __restrict__ embed,
                           const int* __restrict__ csr, const int* __restrict__ rowptr,
                           const float* __restrict__ dinv, float* __restrict__ agg0, int N) {
    int wid = (blockIdx.x * blockDim.x + threadIdx.x) >> 6;  // one wave per node
    if (wid >= N) return;
    int lane = threadIdx.x & 63;
    int d = wid;
    int beg = rowptr[d], end = rowptr[d + 1];
    float dd = dinv[d];
    float acc = embed[(size_t)ids[d] * EMB + lane] * dd * dd;
    for (int i = beg; i < end; ++i) {
        int s = csr[i];
        float w = dinv[s] * dd;
        acc = fmaf(embed[(size_t)ids[s] * EMB + lane], w, acc);
    }
    agg0[(size_t)d * EMB + lane] = acc;
}

// ---------------- layer-1 matmul: relu([Nx64]@[64x128] + b1) ----------------
__global__ __launch_bounds__(256) void k_mm1(const float* __restrict__ in,
                                             const float* __restrict__ W1,
                                             const float* __restrict__ b1,
                                             float* __restrict__ out, int N) {
    __shared__ float rows_t[EMB][68];    // transposed [k][n], 17 KB
    __shared__ float Ws[EMB * HID];      // full W1, 32 KB
    int tid = threadIdx.x;
    int base = blockIdx.x * MMB;
    {
        const float4* wp = (const float4*)W1;
        float4* wsp = (float4*)Ws;
#pragma unroll
        for (int j = 0; j < 8; ++j) wsp[tid + 256 * j] = wp[tid + 256 * j];
    }
    {
        int n = tid >> 2;
        int k0 = (tid & 3) * 16;
        int node = base + n; if (node >= N) node = N - 1;
        const float4* ep = (const float4*)&in[(size_t)node * EMB + k0];
#pragma unroll
        for (int j = 0; j < 4; ++j) {
            float4 v = ep[j];
            int k = k0 + j * 4;
            rows_t[k + 0][n] = v.x; rows_t[k + 1][n] = v.y;
            rows_t[k + 2][n] = v.z; rows_t[k + 3][n] = v.w;
        }
    }
    __syncthreads();
    int n8 = (tid & 7) * 8;
    int c4 = (tid >> 3) * 4;
    float acc[8][4];
#pragma unroll
    for (int i = 0; i < 8; ++i)
#pragma unroll
        for (int j = 0; j < 4; ++j) acc[i][j] = 0.f;
    for (int k = 0; k < EMB; ++k) {
        float4 w = *(const float4*)&Ws[k * HID + c4];
        float4 r0 = *(const float4*)&rows_t[k][n8];
        float4 r1 = *(const float4*)&rows_t[k][n8 + 4];
        float rr[8] = {r0.x, r0.y, r0.z, r0.w, r1.x, r1.y, r1.z, r1.w};
#pragma unroll
        for (int i = 0; i < 8; ++i) {
            acc[i][0] = fmaf(rr[i], w.x, acc[i][0]);
            acc[i][1] = fmaf(rr[i], w.y, acc[i][1]);
            acc[i][2] = fmaf(rr[i], w.z, acc[i][2]);
            acc[i][3] = fmaf(rr[i], w.w, acc[i][3]);
        }
    }
    float4 bb = *(const float4*)&b1[c4];
#pragma unroll
    for (int i = 0; i < 8; ++i) {
        int node = base + n8 + i;
        if (node < N)
            *(float4*)&out[(size_t)node * HID + c4] =
                make_float4(fmaxf(acc[i][0] + bb.x, 0.f), fmaxf(acc[i][1] + bb.y, 0.f),
                            fmaxf(acc[i][2] + bb.z, 0.f), fmaxf(acc[i][3] + bb.w, 0.f));
    }
}

// ---------------- layer-2 matmul: [Nx128]@[128x128] -> fp16 ----------------
__global__ __launch_bounds__(256) void k_mm2(const float* __restrict__ in,
                                             const float* __restrict__ W,
                                             __half* __restrict__ out, int N) {
    __shared__ float rows_t[HID][68];    // 34 KB
    __shared__ float Ws[32 * HID];       // 16 KB
    int tid = threadIdx.x;
    int base = blockIdx.x * MMB;
    {
        int n = tid >> 2;
        int k0 = (tid & 3) * 32;
        int node = base + n; if (node >= N) node = N - 1;
        const float4* ip = (const float4*)&in[(size_t)node * HID + k0];
#pragma unroll
        for (int j = 0; j < 8; ++j) {
            float4 v = ip[j];
            int k = k0 + j * 4;
            rows_t[k + 0][n] = v.x; rows_t[k + 1][n] = v.y;
            rows_t[k + 2][n] = v.z; rows_t[k + 3][n] = v.w;
        }
    }
    int n8 = (tid & 7) * 8;
    int c4 = (tid >> 3) * 4;
    float acc[8][4];
#pragma unroll
    for (int i = 0; i < 8; ++i)
#pragma unroll
        for (int j = 0; j < 4; ++j) acc[i][j] = 0.f;
    for (int q = 0; q < 4; ++q) {
        __syncthreads();
        {
            const float4* wp = (const float4*)&W[q * 32 * HID];
            float4* wsp = (float4*)Ws;
#pragma unroll
            for (int j = 0; j < 4; ++j) wsp[tid + 256 * j] = wp[tid + 256 * j];
        }
        __syncthreads();
        for (int k = 0; k < 32; ++k) {
            float4 w = *(const float4*)&Ws[k * HID + c4];
            float4 r0 = *(const float4*)&rows_t[q * 32 + k][n8];
            float4 r1 = *(const float4*)&rows_t[q * 32 + k][n8 + 4];
            float rr[8] = {r0.x, r0.y, r0.z, r0.w, r1.x, r1.y, r1.z, r1.w};
#pragma unroll
            for (int i = 0; i < 8; ++i) {
                acc[i][0] = fmaf(rr[i], w.x, acc[i][0]);
                acc[i][1] = fmaf(rr[i], w.y, acc[i][1]);
                acc[i][2] = fmaf(rr[i], w.z, acc[i][2]);
                acc[i][3] = fmaf(rr[i], w.w, acc[i][3]);
            }
        }
    }
#pragma unroll
    for (int i = 0; i < 8; ++i) {
        int node = base + n8 + i;
        if (node < N) {
            union { __half2 h[2]; uint2 u; } pk;
            pk.h[0] = __floats2half2_rn(acc[i][0], acc[i][1]);
            pk.h[1] = __floats2half2_rn(acc[i][2], acc[i][3]);
            *(uint2*)&out[(size_t)node * HID + c4] = pk.u;
        }
    }
}

// ---------------- layer-2 CSR gather (fp16 rows, fp32 accum) + bias + relu ----
__global__ void k_gather128h(const __half* __restrict__ h2, const int* __restrict__ csr,
                             const int* __restrict__ rowptr, const float* __restrict__ dinv,
                             const float* __restrict__ bias, float* __restrict__ out, int N) {
    int wid = (blockIdx.x * blockDim.x + threadIdx.x) >> 6;  // one wave per node
    if (wid >= N) return;
    int lane = threadIdx.x & 63;
    int d = wid;
    int beg = rowptr[d], end = rowptr[d + 1];
    float dd = dinv[d];
    const __half2* hr = (const __half2*)h2;   // row = 64 half2
    float2 f = __half22float2(hr[(size_t)d * 64 + lane]);
    float w0 = dd * dd;
    float ax = f.x * w0, ay = f.y * w0;
    for (int i = beg; i < end; ++i) {
        int s = csr[i];
        float w = dinv[s] * dd;
        float2 v = __half22float2(hr[(size_t)s * 64 + lane]);
        ax = fmaf(v.x, w, ax);
        ay = fmaf(v.y, w, ay);
    }
    float2 b = ((const float2*)bias)[lane];
    float2 r;
    r.x = fmaxf(ax + b.x, 0.f);
    r.y = fmaxf(ay + b.y, 0.f);
    ((float2*)out)[(size_t)d * 64 + lane] = r;
}

// ---------------- fused mean-pool + head: one wave per graph ----------------
__global__ void k_pool2(const float* __restrict__ x, const int* __restrict__ gstart,
                        const float* __restrict__ Wout, const float* __restrict__ bout,
                        float* __restrict__ out) {
    int wid = (blockIdx.x * blockDim.x + threadIdx.x) >> 6;  // graph id
    if (wid >= NG) return;
    int lane = threadIdx.x & 63;
    int beg = gstart[wid], end = gstart[wid + 1];
    const float2* rows = (const float2*)x;
    float sx = 0.f, sy = 0.f;
    for (int n = beg; n < end; ++n) {
        float2 v = rows[(size_t)n * 64 + lane];
        sx += v.x; sy += v.y;
    }
    float inv = (end > beg) ? 1.f / (float)(end - beg) : 1.f;
    sx *= inv; sy *= inv;
    float wo0[NCLS], wo1[NCLS];
    {
        const float4* p0 = (const float4*)&Wout[(size_t)(2 * lane) * NCLS];
        const float4* p1 = (const float4*)&Wout[(size_t)(2 * lane + 1) * NCLS];
#pragma unroll
        for (int j = 0; j < 4; ++j) {
            float4 a = p0[j]; wo0[4*j] = a.x; wo0[4*j+1] = a.y; wo0[4*j+2] = a.z; wo0[4*j+3] = a.w;
            float4 b = p1[j]; wo1[4*j] = b.x; wo1[4*j+1] = b.y; wo1[4*j+2] = b.z; wo1[4*j+3] = b.w;
        }
    }
#pragma unroll
    for (int c = 0; c < NCLS; ++c) {
        float p = fmaf(sx, wo0[c], sy * wo1[c]);
#pragma unroll
        for (int s = 1; s < 64; s <<= 1) p += __shfl_xor(p, s, 64);
        if (lane == c) out[(size_t)wid * NCLS + c] = p + bout[c];
    }
}

static inline size_t align_up(size_t v, size_t a) { return (v + a - 1) & ~(a - 1); }

extern "C" void kernel_launch(void* const* d_in, const int* in_sizes, int n_in,
                              void* d_out, int out_size, void* d_ws, size_t ws_size,
                              hipStream_t stream) {
    const int*   node_ids = (const int*)d_in[0];
    const int*   edge     = (const int*)d_in[1];
    const int*   batch    = (const int*)d_in[2];
    const float* embed    = (const float*)d_in[3];
    const float* W1       = (const float*)d_in[4];
    const float* b1       = (const float*)d_in[5];
    const float* W2       = (const float*)d_in[6];
    const float* b2       = (const float*)d_in[7];
    const float* Wout     = (const float*)d_in[8];
    const float* bout     = (const float*)d_in[9];
    float* out = (float*)d_out;

    const int N = in_sizes[0];
    const int E = in_sizes[1] / 2;
    const int seg = (N + SCAN_T - 1) / SCAN_T;

    // 256B-aligned workspace layout
    char* wsb = (char*)d_ws;
    size_t off = 0;
    float* dinv   = (float*)(wsb + off); off = align_up(off + (size_t)N * 4, 256);
    int*   deg    = (int*)(wsb + off);   off = align_up(off + (size_t)N * 4, 256);
    int*   rowptr = (int*)(wsb + off);   off = align_up(off + (size_t)(N + 1) * 4, 256);
    int*   tsum   = (int*)(wsb + off);   off = align_up(off + (size_t)SCAN_T * 4, 256);
    int*   gstart = (int*)(wsb + off);   off = align_up(off + (size_t)(NG + 1) * 4, 256);
    int*   csr    = (int*)(wsb + off);   off = align_up(off + (size_t)E * 4, 256);
    float* agg0   = (float*)(wsb + off); off = align_up(off + (size_t)N * EMB * 4, 256);
    float* B      = (float*)(wsb + off); off = align_up(off + (size_t)N * HID * 4, 256);
    __half* h2    = (__half*)(wsb + off); off = align_up(off + (size_t)N * HID * 2, 256);

    const int* src = edge;
    const int* dst = edge + E;

    // ---- CSR build + boundaries ----
    hipMemsetAsync(deg, 0, (size_t)N * 4, stream);
    k_deg<<<(E + 255) / 256, 256, 0, stream>>>(dst, E, deg);
    k_dinv<<<(N + 255) / 256, 256, 0, stream>>>(deg, dinv, N);
    k_scanA<<<SCAN_T / 256, 256, 0, stream>>>(deg, tsum, N, seg);
    k_scanB<<<1, 256, 0, stream>>>(tsum);
    k_scanC<<<SCAN_T / 256, 256, 0, stream>>>(deg, tsum, rowptr, N, seg, E);
    hipMemsetAsync(deg, 0, (size_t)N * 4, stream);   // reuse as cursor
    k_fill<<<(E + 255) / 256, 256, 0, stream>>>(src, dst, rowptr, deg, csr, E);
    k_bounds<<<(N + 1 + 255) / 256, 256, 0, stream>>>(batch, gstart, N);

    // ---- layer 1: propagate in embed space, then matmul (bias+relu fused) ----
    k_gather64<<<(N * 64 + 255) / 256, 256, 0, stream>>>(node_ids, embed, csr, rowptr, dinv, agg0, N);
    k_mm1<<<(N + MMB - 1) / MMB, 256, 0, stream>>>(agg0, W1, b1, B, N);

    // ---- layer 2: matmul -> fp16, then gather (bias+relu fused), back into B ----
    k_mm2<<<(N + MMB - 1) / MMB, 256, 0, stream>>>(B, W2, h2, N);
    k_gather128h<<<(N * 64 + 255) / 256, 256, 0, stream>>>(h2, csr, rowptr, dinv, b2, B, N);

    // ---- fused pool + head ----
    k_pool2<<<(NG * 64 + 255) / 256, 256, 0, stream>>>(B, gstart, Wout, bout, out);
}

// Round 5
// 324.745 us; speedup vs baseline: 12.2408x; 1.3115x over previous
//
#include <hip/hip_runtime.h>
#include <hip/hip_fp16.h>

#define HID 128
#define EMB 64
#define NG  8192
#define NCLS 16
#define SCAN_T 4096
#define MMB 64        // nodes per matmul block

// ---------------- degree ----------------
__global__ void k_deg(const int* __restrict__ dst, int E, int* __restrict__ deg) {
    int i = blockIdx.x * 256 + threadIdx.x;
    if (i < E) atomicAdd(&deg[dst[i]], 1);
}

__global__ void k_dinv(const int* __restrict__ deg, float* __restrict__ dinv, int N) {
    int i = blockIdx.x * 256 + threadIdx.x;
    if (i < N) dinv[i] = rsqrtf((float)(deg[i] + 1));  // +1 self-loop
}

// ---------------- exclusive scan of deg -> rowptr ----------------
__global__ void k_scanA(const int* __restrict__ deg, int* __restrict__ tsum, int N, int seg) {
    int t = blockIdx.x * 256 + threadIdx.x;
    int beg = t * seg, end = min(beg + seg, N);
    int s = 0;
    for (int i = beg; i < end; ++i) s += deg[i];
    tsum[t] = s;
}

__global__ void k_scanB(int* __restrict__ tsum) {
    __shared__ int sh[256];
    int tid = threadIdx.x;
    const int PER = SCAN_T / 256;
    int vals[PER];
    int local = 0;
    int base = tid * PER;
#pragma unroll
    for (int i = 0; i < PER; ++i) { vals[i] = tsum[base + i]; local += vals[i]; }
    sh[tid] = local; __syncthreads();
    for (int d = 1; d < 256; d <<= 1) {
        int v = (tid >= d) ? sh[tid - d] : 0;
        __syncthreads();
        sh[tid] += v;
        __syncthreads();
    }
    int off = sh[tid] - local;
#pragma unroll
    for (int i = 0; i < PER; ++i) { int v = vals[i]; tsum[base + i] = off; off += v; }
}

__global__ void k_scanC(const int* __restrict__ deg, const int* __restrict__ tsum,
                        int* __restrict__ rowptr, int N, int seg, int E) {
    int t = blockIdx.x * 256 + threadIdx.x;
    int beg = t * seg, end = min(beg + seg, N);
    int off = tsum[t];
    for (int i = beg; i < end; ++i) { rowptr[i] = off; off += deg[i]; }
    if (t == 0) rowptr[N] = E;
}

// ---------------- CSR fill: src node, src vocab-id, src weight ----------------
__global__ void k_fill(const int* __restrict__ src, const int* __restrict__ dst,
                       const int* __restrict__ ids, const float* __restrict__ dinv,
                       const int* __restrict__ rowptr, int* __restrict__ cursor,
                       int* __restrict__ csr_src, int* __restrict__ csr_vid,
                       float* __restrict__ csr_w, int E) {
    int e = blockIdx.x * 256 + threadIdx.x;
    if (e < E) {
        int s = src[e], d = dst[e];
        int pos = atomicAdd(&cursor[d], 1);
        int p = rowptr[d] + pos;
        csr_src[p] = s;
        csr_vid[p] = ids[s];
        csr_w[p]   = dinv[s];
    }
}

// ---------------- graph segment boundaries from sorted batch ----------------
__global__ void k_bounds(const int* __restrict__ batch, int* __restrict__ gstart, int N) {
    int n = blockIdx.x * 256 + threadIdx.x;
    if (n > N) return;
    int bc = (n < N) ? batch[n] : NG;
    int bp = (n > 0) ? batch[n - 1] : -1;
    for (int g = bp + 1; g <= bc; ++g) gstart[g] = n;
}

// ---------------- layer-1 propagate in 64-dim embed space (L2-resident table) ----
// agg0[d] = dd * ( dd*embed[ids[d]] + sum_e w_e * embed[vid_e] )
__global__ void k_gather64(const int* __restrict__ ids, const float* __restrict__ embed,
                           const int* __restrict__ csr_vid, const float* __restrict__ csr_w,
                           const int* __restrict__ rowptr, const float* __restrict__ dinv,
                           float* __restrict__ agg0, int N) {
    int wid = (blockIdx.x * blockDim.x + threadIdx.x) >> 6;  // one wave per node
    if (wid >= N) return;
    int lane = threadIdx.x & 63;
    int d = wid;
    int beg = rowptr[d], end = rowptr[d + 1];
    float dd = dinv[d];
    float acc = embed[(size_t)ids[d] * EMB + lane] * dd;
    int i = beg;
    for (; i + 4 <= end; i += 4) {
        int v0 = csr_vid[i], v1 = csr_vid[i + 1], v2 = csr_vid[i + 2], v3 = csr_vid[i + 3];
        float w0 = csr_w[i], w1 = csr_w[i + 1], w2 = csr_w[i + 2], w3 = csr_w[i + 3];
        float e0 = embed[(size_t)v0 * EMB + lane];
        float e1 = embed[(size_t)v1 * EMB + lane];
        float e2 = embed[(size_t)v2 * EMB + lane];
        float e3 = embed[(size_t)v3 * EMB + lane];
        acc = fmaf(e0, w0, acc);
        acc = fmaf(e1, w1, acc);
        acc = fmaf(e2, w2, acc);
        acc = fmaf(e3, w3, acc);
    }
    for (; i < end; ++i)
        acc = fmaf(embed[(size_t)csr_vid[i] * EMB + lane], csr_w[i], acc);
    agg0[(size_t)d * EMB + lane] = acc * dd;
}

// ---------------- layer-1 matmul: relu([Nx64]@[64x128] + b1) ----------------
__global__ __launch_bounds__(256) void k_mm1(const float* __restrict__ in,
                                             const float* __restrict__ W1,
                                             const float* __restrict__ b1,
                                             float* __restrict__ out, int N) {
    __shared__ float rows_t[EMB][68];    // transposed [k][n], 17 KB
    __shared__ float Ws[EMB * HID];      // full W1, 32 KB
    int tid = threadIdx.x;
    int base = blockIdx.x * MMB;
    {
        const float4* wp = (const float4*)W1;
        float4* wsp = (float4*)Ws;
#pragma unroll
        for (int j = 0; j < 8; ++j) wsp[tid + 256 * j] = wp[tid + 256 * j];
    }
    {
        int n = tid >> 2;
        int k0 = (tid & 3) * 16;
        int node = base + n; if (node >= N) node = N - 1;
        const float4* ep = (const float4*)&in[(size_t)node * EMB + k0];
#pragma unroll
        for (int j = 0; j < 4; ++j) {
            float4 v = ep[j];
            int k = k0 + j * 4;
            rows_t[k + 0][n] = v.x; rows_t[k + 1][n] = v.y;
            rows_t[k + 2][n] = v.z; rows_t[k + 3][n] = v.w;
        }
    }
    __syncthreads();
    int n8 = (tid & 7) * 8;
    int c4 = (tid >> 3) * 4;
    float acc[8][4];
#pragma unroll
    for (int i = 0; i < 8; ++i)
#pragma unroll
        for (int j = 0; j < 4; ++j) acc[i][j] = 0.f;
    for (int k = 0; k < EMB; ++k) {
        float4 w = *(const float4*)&Ws[k * HID + c4];
        float4 r0 = *(const float4*)&rows_t[k][n8];
        float4 r1 = *(const float4*)&rows_t[k][n8 + 4];
        float rr[8] = {r0.x, r0.y, r0.z, r0.w, r1.x, r1.y, r1.z, r1.w};
#pragma unroll
        for (int i = 0; i < 8; ++i) {
            acc[i][0] = fmaf(rr[i], w.x, acc[i][0]);
            acc[i][1] = fmaf(rr[i], w.y, acc[i][1]);
            acc[i][2] = fmaf(rr[i], w.z, acc[i][2]);
            acc[i][3] = fmaf(rr[i], w.w, acc[i][3]);
        }
    }
    float4 bb = *(const float4*)&b1[c4];
#pragma unroll
    for (int i = 0; i < 8; ++i) {
        int node = base + n8 + i;
        if (node < N)
            *(float4*)&out[(size_t)node * HID + c4] =
                make_float4(fmaxf(acc[i][0] + bb.x, 0.f), fmaxf(acc[i][1] + bb.y, 0.f),
                            fmaxf(acc[i][2] + bb.z, 0.f), fmaxf(acc[i][3] + bb.w, 0.f));
    }
}

// ---------------- layer-2 matmul: [Nx128]@[128x128] -> fp16, prescaled by dinv ----
__global__ __launch_bounds__(256) void k_mm2(const float* __restrict__ in,
                                             const float* __restrict__ W,
                                             const float* __restrict__ dinv,
                                             __half* __restrict__ out, int N) {
    __shared__ float rows_t[HID][68];    // 34 KB
    __shared__ float Ws[32 * HID];       // 16 KB
    int tid = threadIdx.x;
    int base = blockIdx.x * MMB;
    {
        int n = tid >> 2;
        int k0 = (tid & 3) * 32;
        int node = base + n; if (node >= N) node = N - 1;
        const float4* ip = (const float4*)&in[(size_t)node * HID + k0];
#pragma unroll
        for (int j = 0; j < 8; ++j) {
            float4 v = ip[j];
            int k = k0 + j * 4;
            rows_t[k + 0][n] = v.x; rows_t[k + 1][n] = v.y;
            rows_t[k + 2][n] = v.z; rows_t[k + 3][n] = v.w;
        }
    }
    int n8 = (tid & 7) * 8;
    int c4 = (tid >> 3) * 4;
    float acc[8][4];
#pragma unroll
    for (int i = 0; i < 8; ++i)
#pragma unroll
        for (int j = 0; j < 4; ++j) acc[i][j] = 0.f;
    for (int q = 0; q < 4; ++q) {
        __syncthreads();
        {
            const float4* wp = (const float4*)&W[q * 32 * HID];
            float4* wsp = (float4*)Ws;
#pragma unroll
            for (int j = 0; j < 4; ++j) wsp[tid + 256 * j] = wp[tid + 256 * j];
        }
        __syncthreads();
        for (int k = 0; k < 32; ++k) {
            float4 w = *(const float4*)&Ws[k * HID + c4];
            float4 r0 = *(const float4*)&rows_t[q * 32 + k][n8];
            float4 r1 = *(const float4*)&rows_t[q * 32 + k][n8 + 4];
            float rr[8] = {r0.x, r0.y, r0.z, r0.w, r1.x, r1.y, r1.z, r1.w};
#pragma unroll
            for (int i = 0; i < 8; ++i) {
                acc[i][0] = fmaf(rr[i], w.x, acc[i][0]);
                acc[i][1] = fmaf(rr[i], w.y, acc[i][1]);
                acc[i][2] = fmaf(rr[i], w.z, acc[i][2]);
                acc[i][3] = fmaf(rr[i], w.w, acc[i][3]);
            }
        }
    }
#pragma unroll
    for (int i = 0; i < 8; ++i) {
        int node = base + n8 + i;
        if (node < N) {
            float sc = dinv[node];
            union { __half2 h[2]; uint2 u; } pk;
            pk.h[0] = __floats2half2_rn(acc[i][0] * sc, acc[i][1] * sc);
            pk.h[1] = __floats2half2_rn(acc[i][2] * sc, acc[i][3] * sc);
            *(uint2*)&out[(size_t)node * HID + c4] = pk.u;
        }
    }
}

// ---------------- layer-2 gather: out[d] = relu(dd*(h2[d]+sum h2[s]) + b) ----
__global__ void k_gather128h(const __half* __restrict__ h2, const int* __restrict__ csr_src,
                             const int* __restrict__ rowptr, const float* __restrict__ dinv,
                             const float* __restrict__ bias, float* __restrict__ out, int N) {
    int wid = (blockIdx.x * blockDim.x + threadIdx.x) >> 6;  // one wave per node
    if (wid >= N) return;
    int lane = threadIdx.x & 63;
    int d = wid;
    int beg = rowptr[d], end = rowptr[d + 1];
    float dd = dinv[d];
    const __half2* hr = (const __half2*)h2;   // row = 64 half2
    float2 f = __half22float2(hr[(size_t)d * 64 + lane]);
    float ax = f.x, ay = f.y;
    int i = beg;
    for (; i + 4 <= end; i += 4) {
        int s0 = csr_src[i], s1 = csr_src[i + 1], s2 = csr_src[i + 2], s3 = csr_src[i + 3];
        float2 v0 = __half22float2(hr[(size_t)s0 * 64 + lane]);
        float2 v1 = __half22float2(hr[(size_t)s1 * 64 + lane]);
        float2 v2 = __half22float2(hr[(size_t)s2 * 64 + lane]);
        float2 v3 = __half22float2(hr[(size_t)s3 * 64 + lane]);
        ax += (v0.x + v1.x) + (v2.x + v3.x);
        ay += (v0.y + v1.y) + (v2.y + v3.y);
    }
    for (; i < end; ++i) {
        float2 v = __half22float2(hr[(size_t)csr_src[i] * 64 + lane]);
        ax += v.x; ay += v.y;
    }
    float2 b = ((const float2*)bias)[lane];
    float2 r;
    r.x = fmaxf(fmaf(ax, dd, b.x), 0.f);
    r.y = fmaxf(fmaf(ay, dd, b.y), 0.f);
    ((float2*)out)[(size_t)d * 64 + lane] = r;
}

// ---------------- fused mean-pool + head: one wave per graph ----------------
__global__ void k_pool2(const float* __restrict__ x, const int* __restrict__ gstart,
                        const float* __restrict__ Wout, const float* __restrict__ bout,
                        float* __restrict__ out) {
    int wid = (blockIdx.x * blockDim.x + threadIdx.x) >> 6;  // graph id
    if (wid >= NG) return;
    int lane = threadIdx.x & 63;
    int beg = gstart[wid], end = gstart[wid + 1];
    const float2* rows = (const float2*)x;
    float sx = 0.f, sy = 0.f;
    for (int n = beg; n < end; ++n) {
        float2 v = rows[(size_t)n * 64 + lane];
        sx += v.x; sy += v.y;
    }
    float inv = (end > beg) ? 1.f / (float)(end - beg) : 1.f;
    sx *= inv; sy *= inv;
    float wo0[NCLS], wo1[NCLS];
    {
        const float4* p0 = (const float4*)&Wout[(size_t)(2 * lane) * NCLS];
        const float4* p1 = (const float4*)&Wout[(size_t)(2 * lane + 1) * NCLS];
#pragma unroll
        for (int j = 0; j < 4; ++j) {
            float4 a = p0[j]; wo0[4*j] = a.x; wo0[4*j+1] = a.y; wo0[4*j+2] = a.z; wo0[4*j+3] = a.w;
            float4 b = p1[j]; wo1[4*j] = b.x; wo1[4*j+1] = b.y; wo1[4*j+2] = b.z; wo1[4*j+3] = b.w;
        }
    }
#pragma unroll
    for (int c = 0; c < NCLS; ++c) {
        float p = fmaf(sx, wo0[c], sy * wo1[c]);
#pragma unroll
        for (int s = 1; s < 64; s <<= 1) p += __shfl_xor(p, s, 64);
        if (lane == c) out[(size_t)wid * NCLS + c] = p + bout[c];
    }
}

static inline size_t align_up(size_t v, size_t a) { return (v + a - 1) & ~(a - 1); }

extern "C" void kernel_launch(void* const* d_in, const int* in_sizes, int n_in,
                              void* d_out, int out_size, void* d_ws, size_t ws_size,
                              hipStream_t stream) {
    const int*   node_ids = (const int*)d_in[0];
    const int*   edge     = (const int*)d_in[1];
    const int*   batch    = (const int*)d_in[2];
    const float* embed    = (const float*)d_in[3];
    const float* W1       = (const float*)d_in[4];
    const float* b1       = (const float*)d_in[5];
    const float* W2       = (const float*)d_in[6];
    const float* b2       = (const float*)d_in[7];
    const float* Wout     = (const float*)d_in[8];
    const float* bout     = (const float*)d_in[9];
    float* out = (float*)d_out;

    const int N = in_sizes[0];
    const int E = in_sizes[1] / 2;
    const int seg = (N + SCAN_T - 1) / SCAN_T;

    // 256B-aligned workspace layout; h2 overlays agg0 (dead after k_mm1)
    char* wsb = (char*)d_ws;
    size_t off = 0;
    float* dinv    = (float*)(wsb + off); off = align_up(off + (size_t)N * 4, 256);
    int*   deg     = (int*)(wsb + off);   off = align_up(off + (size_t)N * 4, 256);
    int*   rowptr  = (int*)(wsb + off);   off = align_up(off + (size_t)(N + 1) * 4, 256);
    int*   tsum    = (int*)(wsb + off);   off = align_up(off + (size_t)SCAN_T * 4, 256);
    int*   gstart  = (int*)(wsb + off);   off = align_up(off + (size_t)(NG + 1) * 4, 256);
    int*   csr_src = (int*)(wsb + off);   off = align_up(off + (size_t)E * 4, 256);
    int*   csr_vid = (int*)(wsb + off);   off = align_up(off + (size_t)E * 4, 256);
    float* csr_w   = (float*)(wsb + off); off = align_up(off + (size_t)E * 4, 256);
    float* agg0    = (float*)(wsb + off);
    __half* h2     = (__half*)(wsb + off); off = align_up(off + (size_t)N * EMB * 4, 256);
    float* B       = (float*)(wsb + off);  off = align_up(off + (size_t)N * HID * 4, 256);

    const int* src = edge;
    const int* dst = edge + E;

    // ---- CSR build + boundaries ----
    hipMemsetAsync(deg, 0, (size_t)N * 4, stream);
    k_deg<<<(E + 255) / 256, 256, 0, stream>>>(dst, E, deg);
    k_dinv<<<(N + 255) / 256, 256, 0, stream>>>(deg, dinv, N);
    k_scanA<<<SCAN_T / 256, 256, 0, stream>>>(deg, tsum, N, seg);
    k_scanB<<<1, 256, 0, stream>>>(tsum);
    k_scanC<<<SCAN_T / 256, 256, 0, stream>>>(deg, tsum, rowptr, N, seg, E);
    hipMemsetAsync(deg, 0, (size_t)N * 4, stream);   // reuse as cursor
    k_fill<<<(E + 255) / 256, 256, 0, stream>>>(src, dst, node_ids, dinv, rowptr, deg,
                                                csr_src, csr_vid, csr_w, E);
    k_bounds<<<(N + 1 + 255) / 256, 256, 0, stream>>>(batch, gstart, N);

    // ---- layer 1: propagate in embed space, then matmul (bias+relu fused) ----
    k_gather64<<<(N * 64 + 255) / 256, 256, 0, stream>>>(node_ids, embed, csr_vid, csr_w,
                                                         rowptr, dinv, agg0, N);
    k_mm1<<<(N + MMB - 1) / MMB, 256, 0, stream>>>(agg0, W1, b1, B, N);

    // ---- layer 2: matmul -> fp16 (prescaled by dinv), gather, back into B ----
    k_mm2<<<(N + MMB - 1) / MMB, 256, 0, stream>>>(B, W2, dinv, h2, N);
    k_gather128h<<<(N * 64 + 255) / 256, 256, 0, stream>>>(h2, csr_src, rowptr, dinv, b2, B, N);

    // ---- fused pool + head ----
    k_pool2<<<(NG * 64 + 255) / 256, 256, 0, stream>>>(B, gstart, Wout, bout, out);
}